// Round 6
// baseline (331.466 us; speedup 1.0000x reference)
//
#include <hip/hip_runtime.h>
#include <math.h>

#define KTOP 16
#define T1   256                 // pass-1 threads per block
#define B1   2048                // pass-1 blocks: 8 blocks/CU, 32 waves/CU
#define WPB  (T1 / 64)           // 4 waves per block
#define NW   (B1 * WPB)          // 8192 waves total
#define SEG  128                 // points per wave-iteration (192 float4)
#define T2   1024                // pass-2 threads
#define NC2  (B1 * KTOP)         // 32768 candidates

typedef unsigned long long ull;

// Sortable key: larger distance first, ties -> smaller index first.
__device__ __forceinline__ ull pack_key(float d, unsigned idx) {
    return ((ull)__float_as_uint(d) << 32) | (ull)(0xFFFFFFFFu - idx);
}

// Sorted-descending bubble insert, constant indices only (SROA-safe).
__device__ __forceinline__ void insert_key(ull (&k)[KTOP], ull key) {
    ull t = key;
#pragma unroll
    for (int j = 0; j < KTOP; ++j) {
        const ull a = k[j];
        const bool c = (t > a);
        k[j] = c ? t : a;
        t    = c ? a : t;
    }
}

__device__ __forceinline__ float dist3(float x, float y, float z,
                                       float px, float py, float pz) {
#pragma clang fp contract(off)
    const float dx = x - px;
    const float dy = y - py;
    const float dz = z - pz;
    const float s  = (dx * dx + dy * dy) + dz * dz;
    return sqrtf(s);
}

__global__ __launch_bounds__(T1, 4) void pass1_topk(const float* __restrict__ P,
                                                    const int*   __restrict__ ipq,
                                                    int n,
                                                    ull* __restrict__ cand) {
    const int tid  = threadIdx.x;
    const int lane = tid & 63;
    const int wid  = tid >> 6;

    const int i0 = ipq[0];
    const float pix = P[6 * i0 + 0];
    const float piy = P[6 * i0 + 1];
    const float piz = P[6 * i0 + 2];

    ull k[KTOP];
#pragma unroll
    for (int j = 0; j < KTOP; ++j) k[j] = 0ull;

    const float4* __restrict__ P4 = (const float4*)P;
    const int nSeg = n / SEG;
    const int gw   = blockIdx.x * WPB + wid;   // global wave id

    const int r3 = lane % 3;
    const int t3 = lane / 3;
    // Even/odd point offsets within the 128-point segment (derived from the
    // role algebra; verified for lanes 0,1,2,63).
    const unsigned peOff = 2u * t3 + ((r3 == 0) ? 0u  : (r3 == 1) ? 86u : 44u);
    const unsigned poOff = 2u * t3 + ((r3 == 0) ? 43u : (r3 == 1) ? 1u  : 87u);

    for (int s = gw; s < nSeg; s += NW) {
        // 3 lane-contiguous dwordx4 loads: 16 cachelines per instruction.
        const float4* __restrict__ src = P4 + (size_t)s * (3 * 64);
        const float4 qa = src[lane];
        const float4 qb = src[lane + 64];
        const float4 qc = src[lane + 128];

        float s0a, s0b, s0c, s1a, s1b, s1c, z2a, z2b, z2c;
        {
#pragma clang fp contract(off)
            { const float dx = qa.x - pix, dy = qa.y - piy, dz = qa.z - piz;
              s0a = (dx * dx + dy * dy) + dz * dz;
              const float ex = qa.z - pix, ey = qa.w - piy;
              s1a = ex * ex + ey * ey;
              const float zz = qa.x - piz; z2a = zz * zz; }
            { const float dx = qb.x - pix, dy = qb.y - piy, dz = qb.z - piz;
              s0b = (dx * dx + dy * dy) + dz * dz;
              const float ex = qb.z - pix, ey = qb.w - piy;
              s1b = ex * ex + ey * ey;
              const float zz = qb.x - piz; z2b = zz * zz; }
            { const float dx = qc.x - pix, dy = qc.y - piy, dz = qc.z - piz;
              s0c = (dx * dx + dy * dy) + dz * dz;
              const float ex = qc.z - pix, ey = qc.w - piy;
              s1c = ex * ex + ey * ey;
              const float zz = qc.x - piz; z2c = zz * zz; }
        }

        // Partner z² via in-register shuffles (real dependencies -> no race).
        const float z2na = __shfl_down(z2a, 1);
        float       z2nb = __shfl_down(z2b, 1);
        const float z2nc = __shfl_down(z2c, 1);
        const float zc0  = __shfl(z2c, 0);
        if (lane == 63) z2nb = zc0;            // chunk-boundary pair (f4 127|128)

        // Each lane owns exactly one even and one odd point per iteration.
        const float sfull = (r3 == 0) ? s0a : (r3 == 1) ? s0c : s0b;
        const float spart = (r3 == 0) ? s1b : (r3 == 1) ? s1a : s1c;
        const float zpart = (r3 == 0) ? z2nb : (r3 == 1) ? z2na : z2nc;

        float d_e, d_o;
        {
#pragma clang fp contract(off)
            d_e = sqrtf(sfull);
            d_o = sqrtf(spart + zpart);        // ((dx²+dy²)+dz²) ordering
        }

        const unsigned base = (unsigned)s * (unsigned)SEG;
        const ull k0 = pack_key(d_e, base + peOff);
        const ull k1 = pack_key(d_o, base + poOff);
        if (k0 > k[KTOP - 1]) insert_key(k, k0);
        if (k1 > k[KTOP - 1]) insert_key(k, k1);
    }

    // Remainder points (n % 128) — scalar grid-stride (empty for n=8M).
    for (int p = nSeg * SEG + blockIdx.x * T1 + tid; p < n; p += B1 * T1) {
        const float d = dist3(P[6 * p], P[6 * p + 1], P[6 * p + 2], pix, piy, piz);
        const ull key = pack_key(d, (unsigned)p);
        if (key > k[KTOP - 1]) insert_key(k, key);
    }

    // Block pop-max: 16 rounds, emit block top-16 sorted descending.
    __shared__ ull s_w[WPB];
    __shared__ ull s_best;

    for (int r = 0; r < KTOP; ++r) {
        const ull mk = k[0];
        ull rv = mk;
#pragma unroll
        for (int m = 32; m >= 1; m >>= 1) {
            const ull ov = __shfl_xor(rv, m);
            if (ov > rv) rv = ov;
        }
        if (lane == 0) s_w[wid] = rv;
        __syncthreads();
        if (tid == 0) {
            ull bb = s_w[0];
            for (int w = 1; w < WPB; ++w) if (s_w[w] > bb) bb = s_w[w];
            s_best = bb;
            cand[blockIdx.x * KTOP + r] = bb;
        }
        __syncthreads();
        if (mk == s_best) {   // unique keys -> exactly one owner
#pragma unroll
            for (int j = 0; j < KTOP - 1; ++j) k[j] = k[j + 1];
            k[KTOP - 1] = 0ull;
        }
    }
}

__global__ __launch_bounds__(T2, 1) void pass2_final(const float* __restrict__ P,
                                                     const int*   __restrict__ ipq,
                                                     const float* __restrict__ W,
                                                     const float* __restrict__ bvec,
                                                     const ull*   __restrict__ cand,
                                                     float* __restrict__ out) {
    __shared__ ull s_w[T2 / 64];
    __shared__ ull s_best;
    __shared__ ull s_final[KTOP];

    const int tid  = threadIdx.x;
    const int lane = tid & 63;
    const int wid  = tid >> 6;

    ull k[KTOP];
#pragma unroll
    for (int j = 0; j < KTOP; ++j) k[j] = 0ull;

    for (int c = tid; c < NC2; c += T2) {      // coalesced dwordx2 stream
        const ull key = cand[c];
        if (key > k[KTOP - 1]) insert_key(k, key);
    }

    for (int r = 0; r < KTOP; ++r) {
        const ull mk = k[0];
        ull rv = mk;
#pragma unroll
        for (int m = 32; m >= 1; m >>= 1) {
            const ull ov = __shfl_xor(rv, m);
            if (ov > rv) rv = ov;
        }
        if (lane == 0) s_w[wid] = rv;
        __syncthreads();
        if (tid == 0) {
            ull bb = s_w[0];
            for (int w = 1; w < T2 / 64; ++w) if (s_w[w] > bb) bb = s_w[w];
            s_best = bb;
            s_final[r] = bb;
        }
        __syncthreads();
        if (mk == s_best) {
#pragma unroll
            for (int j = 0; j < KTOP - 1; ++j) k[j] = k[j + 1];
            k[KTOP - 1] = 0ull;
        }
    }
    __syncthreads();

    // Epilogue: 16 threads build feat, apply W,b, write [nloc | R].
    if (tid < KTOP) {
        const ull kk = s_final[tid];
        const float d = __uint_as_float((unsigned)(kk >> 32));
        const unsigned idx = 0xFFFFFFFFu - (unsigned)(kk & 0xFFFFFFFFull);
        const int   i0  = ipq[0];
        const float pix = P[6 * i0 + 0], piy = P[6 * i0 + 1], piz = P[6 * i0 + 2];
        const float nx  = P[6 * (size_t)idx + 0];
        const float ny  = P[6 * (size_t)idx + 1];
        const float nz  = P[6 * (size_t)idx + 2];
        float dx, dy, dz;
        {
#pragma clang fp contract(off)
            dx = pix - nx; dy = piy - ny; dz = piz - nz;
        }
        const float feat[10] = { pix, piy, piz, nx, ny, nz, dx, dy, dz, d };
        float R[3];
#pragma unroll
        for (int r = 0; r < 3; ++r) {
            float acc = bvec[r];
#pragma unroll
            for (int c = 0; c < 10; ++c) acc += feat[c] * W[r * 10 + c];
            R[r] = acc;
        }
        out[6 * tid + 0] = nx;   out[6 * tid + 1] = ny;   out[6 * tid + 2] = nz;
        out[6 * tid + 3] = R[0]; out[6 * tid + 4] = R[1]; out[6 * tid + 5] = R[2];
    }
}

extern "C" void kernel_launch(void* const* d_in, const int* in_sizes, int n_in,
                              void* d_out, int out_size, void* d_ws, size_t ws_size,
                              hipStream_t stream) {
    const float* P    = (const float*)d_in[0];
    const float* W    = (const float*)d_in[1];
    const float* bvec = (const float*)d_in[2];
    const int*   ipq  = (const int*)d_in[3];
    float*       out  = (float*)d_out;

    const int n = in_sizes[0] / 6;
    ull* cand = (ull*)d_ws;

    pass1_topk<<<B1, T1, 0, stream>>>(P, ipq, n, cand);
    pass2_final<<<1, T2, 0, stream>>>(P, ipq, W, bvec, cand, out);
}

// Round 7
// 291.432 us; speedup vs baseline: 1.1374x; 1.1374x over previous
//
#include <hip/hip_runtime.h>
#include <math.h>

// Consolidated best (R2/R3 hybrid):
//   pass1: per-lane strided 6x dwordx4 (96 B/thread/iter), 512x512, lb(512,4).
//     Measured equal-best (~58 us) across R1/R2/R3; coalesced variants (LDS
//     tile w/ barriers, shuffle reassembly) both measured ~100 us — the
//     strided stream is empirically this machine's best pattern here.
//   pass2: B1 == T2, thread t adopts block t's sorted 16 keys in registers.
#define KTOP 16
#define B1   512     // pass-1 blocks (== T2)
#define T1   512     // pass-1 threads per block
#define T2   512     // pass-2 threads

typedef unsigned long long ull;

// Sortable key: larger distance first, ties -> smaller index first.
// d >= 0 so its float bits are monotone in value.
__device__ __forceinline__ ull pack_key(float d, unsigned idx) {
    return ((ull)__float_as_uint(d) << 32) | (ull)(0xFFFFFFFFu - idx);
}

// Sorted-descending bubble insert, constant indices only (SROA-safe).
__device__ __forceinline__ void insert_key(ull (&k)[KTOP], ull key) {
    ull t = key;
#pragma unroll
    for (int j = 0; j < KTOP; ++j) {
        const ull a = k[j];
        const bool c = (t > a);
        k[j] = c ? t : a;
        t    = c ? a : t;
    }
}

__device__ __forceinline__ float dist3(float x, float y, float z,
                                       float px, float py, float pz) {
#pragma clang fp contract(off)
    const float dx = x - px;
    const float dy = y - py;
    const float dz = z - pz;
    const float s  = (dx * dx + dy * dy) + dz * dz;
    return sqrtf(s);
}

__global__ __launch_bounds__(T1, 4) void pass1_topk(const float* __restrict__ P,
                                                    const int*   __restrict__ ipq,
                                                    int n,
                                                    ull* __restrict__ cand) {
    const int tid    = threadIdx.x;
    const int gid    = blockIdx.x * T1 + tid;
    const int stride = B1 * T1;

    const int i0 = ipq[0];
    const float pix = P[6 * i0 + 0];
    const float piy = P[6 * i0 + 1];
    const float piz = P[6 * i0 + 2];

    ull k[KTOP];
#pragma unroll
    for (int j = 0; j < KTOP; ++j) k[j] = 0ull;

    const float4* __restrict__ P4 = (const float4*)P;
    const int nQuad = n >> 2;   // 4 points = 6 float4 = 96 B per quad-group

    for (int q = gid; q < nQuad; q += stride) {
        // 6 dwordx4 in flight per thread per iteration.
        const float4 r0 = P4[6 * q + 0];
        const float4 r1 = P4[6 * q + 1];
        const float4 r2 = P4[6 * q + 2];
        const float4 r3 = P4[6 * q + 3];
        const float4 r4 = P4[6 * q + 4];
        const float4 r5 = P4[6 * q + 5];
        // points 4q..4q+3: (r0.xyz), (r1.z,r1.w,r2.x), (r3.xyz), (r4.z,r4.w,r5.x)
        const float d0 = dist3(r0.x, r0.y, r0.z, pix, piy, piz);
        const float d1 = dist3(r1.z, r1.w, r2.x, pix, piy, piz);
        const float d2 = dist3(r3.x, r3.y, r3.z, pix, piy, piz);
        const float d3 = dist3(r4.z, r4.w, r5.x, pix, piy, piz);
        const ull k0 = pack_key(d0, (unsigned)(4 * q + 0));
        const ull k1 = pack_key(d1, (unsigned)(4 * q + 1));
        const ull k2 = pack_key(d2, (unsigned)(4 * q + 2));
        const ull k3 = pack_key(d3, (unsigned)(4 * q + 3));
        if (k0 > k[KTOP - 1]) insert_key(k, k0);
        if (k1 > k[KTOP - 1]) insert_key(k, k1);
        if (k2 > k[KTOP - 1]) insert_key(k, k2);
        if (k3 > k[KTOP - 1]) insert_key(k, k3);
    }
    // Tail (n not divisible by 4)
    for (int p = (nQuad << 2) + gid; p < n; p += stride) {
        const float d = dist3(P[6 * p], P[6 * p + 1], P[6 * p + 2], pix, piy, piz);
        const ull key = pack_key(d, (unsigned)p);
        if (key > k[KTOP - 1]) insert_key(k, key);
    }

    // Block pop-max: 16 rounds, emit block top-16 sorted descending.
    __shared__ ull s_w[T1 / 64];
    __shared__ ull s_best;
    const int lane = tid & 63;
    const int wid  = tid >> 6;

    for (int r = 0; r < KTOP; ++r) {
        const ull mk = k[0];
        ull rv = mk;
#pragma unroll
        for (int m = 32; m >= 1; m >>= 1) {
            const ull ov = __shfl_xor(rv, m);
            if (ov > rv) rv = ov;
        }
        if (lane == 0) s_w[wid] = rv;
        __syncthreads();
        if (tid == 0) {
            ull b = s_w[0];
            for (int w = 1; w < T1 / 64; ++w) if (s_w[w] > b) b = s_w[w];
            s_best = b;
            cand[blockIdx.x * KTOP + r] = b;
        }
        __syncthreads();
        if (mk == s_best) {   // unique keys -> exactly one owner
#pragma unroll
            for (int j = 0; j < KTOP - 1; ++j) k[j] = k[j + 1];
            k[KTOP - 1] = 0ull;
        }
    }
}

// Thread t adopts pass-1 block t's sorted 16 keys in registers; 16 rounds of
// block pop-max; 16-thread epilogue.
__global__ __launch_bounds__(T2, 1) void pass2_final(const float* __restrict__ P,
                                                     const int*   __restrict__ ipq,
                                                     const float* __restrict__ W,
                                                     const float* __restrict__ bvec,
                                                     const ull*   __restrict__ cand,
                                                     float* __restrict__ out) {
    __shared__ ull s_w[T2 / 64];
    __shared__ ull s_best;
    __shared__ ull s_final[KTOP];

    const int tid  = threadIdx.x;
    const int lane = tid & 63;
    const int wid  = tid >> 6;

    ull k[KTOP];
    const ull* __restrict__ my = cand + (size_t)tid * KTOP;
#pragma unroll
    for (int j = 0; j < KTOP; ++j) k[j] = my[j];   // already sorted descending

    for (int r = 0; r < KTOP; ++r) {
        const ull mk = k[0];
        ull rv = mk;
#pragma unroll
        for (int m = 32; m >= 1; m >>= 1) {
            const ull ov = __shfl_xor(rv, m);
            if (ov > rv) rv = ov;
        }
        if (lane == 0) s_w[wid] = rv;
        __syncthreads();
        if (tid == 0) {
            ull b = s_w[0];
            for (int w = 1; w < T2 / 64; ++w) if (s_w[w] > b) b = s_w[w];
            s_best = b;
            s_final[r] = b;
        }
        __syncthreads();
        if (mk == s_best) {
#pragma unroll
            for (int j = 0; j < KTOP - 1; ++j) k[j] = k[j + 1];
            k[KTOP - 1] = 0ull;
        }
    }
    __syncthreads();

    // Epilogue: 16 threads build feat, apply W,b, write [nloc | R].
    if (tid < KTOP) {
        const ull kk = s_final[tid];
        const float d = __uint_as_float((unsigned)(kk >> 32));
        const unsigned idx = 0xFFFFFFFFu - (unsigned)(kk & 0xFFFFFFFFull);
        const int   i0  = ipq[0];
        const float pix = P[6 * i0 + 0], piy = P[6 * i0 + 1], piz = P[6 * i0 + 2];
        const float nx  = P[6 * (size_t)idx + 0];
        const float ny  = P[6 * (size_t)idx + 1];
        const float nz  = P[6 * (size_t)idx + 2];
        float dx, dy, dz;
        {
#pragma clang fp contract(off)
            dx = pix - nx; dy = piy - ny; dz = piz - nz;
        }
        const float feat[10] = { pix, piy, piz, nx, ny, nz, dx, dy, dz, d };
        float R[3];
#pragma unroll
        for (int r = 0; r < 3; ++r) {
            float acc = bvec[r];
#pragma unroll
            for (int c = 0; c < 10; ++c) acc += feat[c] * W[r * 10 + c];
            R[r] = acc;
        }
        out[6 * tid + 0] = nx;   out[6 * tid + 1] = ny;   out[6 * tid + 2] = nz;
        out[6 * tid + 3] = R[0]; out[6 * tid + 4] = R[1]; out[6 * tid + 5] = R[2];
    }
}

extern "C" void kernel_launch(void* const* d_in, const int* in_sizes, int n_in,
                              void* d_out, int out_size, void* d_ws, size_t ws_size,
                              hipStream_t stream) {
    const float* P    = (const float*)d_in[0];
    const float* W    = (const float*)d_in[1];
    const float* bvec = (const float*)d_in[2];
    const int*   ipq  = (const int*)d_in[3];
    float*       out  = (float*)d_out;

    const int n = in_sizes[0] / 6;
    ull* cand = (ull*)d_ws;

    pass1_topk<<<B1, T1, 0, stream>>>(P, ipq, n, cand);
    pass2_final<<<1, T2, 0, stream>>>(P, ipq, W, bvec, cand, out);
}